// Round 26
// baseline (80.920 us; speedup 1.0000x reference)
//
#include <hip/hip_runtime.h>
#include <hip/hip_bf16.h>

typedef __attribute__((ext_vector_type(4)))  float f32x4;
typedef __attribute__((ext_vector_type(8)))  int   i32x8;
typedef __attribute__((ext_vector_type(4)))  int   i32x4;

static constexpr int NROW = 8192;
static constexpr int DDIM = 512;
static constexpr float INV_T = 10.0f;    // 1 / temperature
static constexpr float SHIFT = 70.0f;    // fixed logsumexp shift (logit max ~60)
// exp(acc*10 - 70) = exp2(acc*14.4269504 - 100.98865)
static constexpr float E2_SC = 14.4269504089f;
static constexpr float E2_BI = -100.988652759f;
static constexpr unsigned SCALE1 = 0x7F7F7F7Fu;   // e8m0 = 127 -> 2^0 = 1.0

__device__ __forceinline__ void gload_lds16(const void* gsrc, void* ldst) {
  __builtin_amdgcn_global_load_lds(
      (const __attribute__((address_space(1))) unsigned int*)gsrc,
      (__attribute__((address_space(3))) unsigned int*)ldst, 16, 0, 0);
}

// single-instruction v_exp_f32 (arg range here is [-187,-14]: no edge cases)
__device__ __forceinline__ float fast_exp2(float x) {
#if __has_builtin(__builtin_amdgcn_exp2f)
  return __builtin_amdgcn_exp2f(x);
#else
  float r;
  asm("v_exp_f32 %0, %1" : "=v"(r) : "v"(x));
  return r;
#endif
}

// pack 4 floats into 4 fp8 e4m3 bytes (gfx950: OCP encoding)
__device__ __forceinline__ unsigned int pack_fp8x4(float x, float y, float z, float w) {
  unsigned int r = 0;
  r = __builtin_amdgcn_cvt_pk_fp8_f32(x, y, r, false);  // bytes 0,1
  r = __builtin_amdgcn_cvt_pk_fp8_f32(z, w, r, true);   // bytes 2,3
  return r;
}

// ---------- prep: normalize anchors, cast to fp8, EXACT fp32 diagonal ----------
__global__ void prep_kernel(const float* __restrict__ f0,
                            const float* __restrict__ f1,
                            unsigned int* __restrict__ A,   // [NROW][DDIM] fp8
                            unsigned int* __restrict__ B,
                            float* __restrict__ wsS,        // [NROW] exp-sums (zeroed)
                            float* __restrict__ wsPosRow,   // [NROW] exact pos_i
                            int* __restrict__ wsCnt) {      // block-done counter
  int gid  = blockIdx.x * blockDim.x + threadIdx.x;
  if (gid < NROW) wsS[gid] = 0.f;             // zero LSE accumulators
  if (gid == 0) *wsCnt = 0;                   // zero done-counter (each call)
  int wid  = gid >> 6;                         // one wave per row
  int lane = threadIdx.x & 63;
  const float4* s0 = (const float4*)(f0 + (size_t)wid * (2 * DDIM));  // features[:,0,:]
  const float4* s1 = (const float4*)(f1 + (size_t)wid * (2 * DDIM));  // features1[:,0,:]
  float4 v0 = s0[lane], v1 = s0[lane + 64];
  float4 w0 = s1[lane], w1 = s1[lane + 64];
  float ss = v0.x * v0.x + v0.y * v0.y + v0.z * v0.z + v0.w * v0.w +
             v1.x * v1.x + v1.y * v1.y + v1.z * v1.z + v1.w * v1.w;
  float cc = v0.x * w0.x + v0.y * w0.y + v0.z * w0.z + v0.w * w0.w +
             v1.x * w1.x + v1.y * w1.y + v1.z * w1.z + v1.w * w1.w;
#pragma unroll
  for (int m = 1; m < 64; m <<= 1) {
    ss += __shfl_xor(ss, m);
    cc += __shfl_xor(cc, m);
  }
  float rn = rsqrtf(ss);
  if (lane == 0) wsPosRow[wid] = cc * rn * INV_T;   // exact fp32 diagonal logit
  A[wid * 128 + lane]      = pack_fp8x4(v0.x * rn, v0.y * rn, v0.z * rn, v0.w * rn);
  A[wid * 128 + 64 + lane] = pack_fp8x4(v1.x * rn, v1.y * rn, v1.z * rn, v1.w * rn);
  B[wid * 128 + lane]      = pack_fp8x4(w0.x, w0.y, w0.z, w0.w);
  B[wid * 128 + 64 + lane] = pack_fp8x4(w1.x, w1.y, w1.z, w1.w);
}

// ---------- fused S = A.B^T / T with fixed-shift LSE + fused finalize ----------
// r24 base (PROVEN best: 16x16x128 MX scales=1.0, 8 waves x M_wave=32,
// 512-thr/128-VGPR class, counted-vmcnt never-drain pipeline) with two trims:
//  * prefetch depth 3 (4 x 32 KiB buffers): steady-state wait vmcnt(8) = own
//    t+1 loads (4) landed while t+2,t+3 (8) stay in flight; tail 8->4->0.
//  * finalize FUSED: last-finishing block (device atomic counter) re-reads
//    wsS via atomic reads (cross-XCD-safe) and reduces to out[0] — removes a
//    kernel launch + gap.
__global__ __launch_bounds__(512, 2) void sim_lse_kernel(
    const unsigned char* __restrict__ Ag,
    const unsigned char* __restrict__ Bg,
    float* __restrict__ wsS,
    const float* __restrict__ wsPosRow,
    int* __restrict__ wsCnt,
    float* __restrict__ out) {
  __shared__ __align__(16) char buf0[64 * 512];   // 32 KiB each; tiles t%4
  __shared__ __align__(16) char buf1[64 * 512];
  __shared__ __align__(16) char buf2[64 * 512];
  __shared__ __align__(16) char buf3[64 * 512];

  const int tid  = threadIdx.x;
  const int w    = tid >> 6;                 // wave 0..7
  const int lane = tid & 63;
  const int lr   = lane & 15;                // row (A) / col (B,D) within 16
  const int kg   = lane >> 4;                // k-group 0..3 (32 B each)

  const int p  = blockIdx.x >> 3;            // row panel 0..31 (256 rows)
  const int cs = blockIdx.x & 7;             // col split 0..7 (1024 cols)
  const int r0 = p * 256 + w * 32;           // this wave's first row (32 rows)
  const int c0 = cs * 1024;                  // first column of this split

  // staging (verbatim r8/r23/r24): wave w stages row-pairs pr = it*8+w; lane
  // covers 16 B of row n = 2*pr + (lane>>5); src byte ((lane&31)<<4)^((n&7)<<4)
  const int h5      = lane >> 5;
  const int stg_off = ((lane & 31) << 4) ^ (((2 * w + h5) & 7) << 4);
  const int stg_row = h5;
  const int swz = (lr & 7) << 4;             // col&7 == lr&7 (16 | jb*16)

  // A fragments, K-resident, 2 row-blocks of 16:
  // aX[ks] = 32 B of A[r0 + X*16 + lr][ks*128 + kg*32 .. +32)
  i32x8 a0[4], a1[4];
  {
    const char* ar0 = (const char*)Ag + (size_t)(r0 + lr) * DDIM + kg * 32;
    const char* ar1 = (const char*)Ag + (size_t)(r0 + 16 + lr) * DDIM + kg * 32;
#pragma unroll
    for (int ks = 0; ks < 4; ks++) {
      a0[ks] = *(const i32x8*)(ar0 + ks * 128);
      a1[ks] = *(const i32x8*)(ar1 + ks * 128);
    }
  }

  float sums0[4], sums1[4];
#pragma unroll
  for (int r = 0; r < 4; r++) { sums0[r] = 0.f; sums1[r] = 0.f; }

#define STAGE(BUF, T)                                                          \
  {                                                                            \
    const char* gb = (const char*)Bg + (size_t)(c0 + (T) * 64) * DDIM;         \
    _Pragma("unroll")                                                          \
    for (int it = 0; it < 4; it++) {                                           \
      int pr = it * 8 + w;                                                     \
      gload_lds16(gb + (size_t)(2 * pr + stg_row) * DDIM + stg_off,            \
                  (char*)(BUF) + pr * 1024);                                   \
    }                                                                          \
  }

// One tile (64 cols = 4 jb of 16): per jb, 4 k-steps; B-frag shared by the
// two row-block chains (acc0/acc1 interleave).
#define MFMA_EPI(BUF)                                                          \
  {                                                                            \
    _Pragma("unroll")                                                          \
    for (int jb = 0; jb < 4; jb++) {                                           \
      const int cb = ((jb * 16 + lr) * 512 + kg * 32) ^ swz;                   \
      const char* p0  = (const char*)(BUF) + cb;                               \
      const char* p0x = (const char*)(BUF) + (cb ^ 16);                        \
      f32x4 acc0 = (f32x4){0.f, 0.f, 0.f, 0.f};                                \
      f32x4 acc1 = (f32x4){0.f, 0.f, 0.f, 0.f};                                \
      __builtin_amdgcn_s_setprio(1);                                           \
      _Pragma("unroll")                                                        \
      for (int ks = 0; ks < 4; ks++) {                                         \
        i32x8 bv = __builtin_shufflevector(                                    \
            *(const i32x4*)(p0 + ks * 128), *(const i32x4*)(p0x + ks * 128),   \
            0, 1, 2, 3, 4, 5, 6, 7);                                           \
        acc0 = __builtin_amdgcn_mfma_scale_f32_16x16x128_f8f6f4(               \
            a0[ks], bv, acc0, 0, 0, 0, SCALE1, 0, SCALE1);                     \
        acc1 = __builtin_amdgcn_mfma_scale_f32_16x16x128_f8f6f4(               \
            a1[ks], bv, acc1, 0, 0, 0, SCALE1, 0, SCALE1);                     \
      }                                                                        \
      __builtin_amdgcn_s_setprio(0);                                           \
      _Pragma("unroll")                                                        \
      for (int r = 0; r < 4; r++) {                                            \
        sums0[r] += fast_exp2(fmaf(acc0[r], E2_SC, E2_BI));                    \
        sums1[r] += fast_exp2(fmaf(acc1[r], E2_SC, E2_BI));                    \
      }                                                                        \
    }                                                                          \
  }

// counted-vmcnt barriers (depth-3): own t+1 loads done, deeper stay in flight.
#define WAITBAR(N)                                                             \
  {                                                                            \
    asm volatile("s_waitcnt vmcnt(" #N ")" ::: "memory");                      \
    __builtin_amdgcn_s_barrier();                                              \
  }

  STAGE(buf0, 0);
  STAGE(buf1, 1);
  STAGE(buf2, 2);
  WAITBAR(8);                                 // tile 0 landed; 1,2 in flight

#pragma unroll 1
  for (int i = 0; i < 3; i++) {               // tiles 4i .. 4i+3, stage 3..14
    const int t = 4 * i;
    MFMA_EPI(buf0);  STAGE(buf3, t + 3);  WAITBAR(8);
    MFMA_EPI(buf1);  STAGE(buf0, t + 4);  WAITBAR(8);
    MFMA_EPI(buf2);  STAGE(buf1, t + 5);  WAITBAR(8);
    MFMA_EPI(buf3);  STAGE(buf2, t + 6);  WAITBAR(8);
  }
  MFMA_EPI(buf0);  STAGE(buf3, 15);  WAITBAR(8);   // t=12; 13,14,15 staged
  MFMA_EPI(buf1);  WAITBAR(4);                     // t=13; 14 landed
  MFMA_EPI(buf2);  WAITBAR(0);                     // t=14; 15 landed
  MFMA_EPI(buf3);                                  // t=15

#undef STAGE
#undef MFMA_EPI
#undef WAITBAR

  // reduce over the 16 col-partition lanes (same kg); lane lr==0 commits.
  // Lane's rows: r0 + rb*16 + kg*4 + r  (C/D row = (lane>>4)*4 + reg, m89).
#pragma unroll
  for (int r = 0; r < 4; r++) {
    float s0 = sums0[r], s1 = sums1[r];
    s0 += __shfl_xor(s0, 1);  s1 += __shfl_xor(s1, 1);
    s0 += __shfl_xor(s0, 2);  s1 += __shfl_xor(s1, 2);
    s0 += __shfl_xor(s0, 4);  s1 += __shfl_xor(s1, 4);
    s0 += __shfl_xor(s0, 8);  s1 += __shfl_xor(s1, 8);
    if (lr == 0) {
      atomicAdd(&wsS[r0 + kg * 4 + r], s0);
      atomicAdd(&wsS[r0 + 16 + kg * 4 + r], s1);
    }
  }

  // ---- fused finalize: last block to finish reduces wsS -> out[0] ----
  __threadfence();                            // our wsS adds globally visible
  __syncthreads();                            // all waves committed
  int* flag = (int*)buf0;                     // reuse LDS (compute done)
  if (tid == 0) flag[0] = (atomicAdd(wsCnt, 1) == 255) ? 1 : 0;
  __syncthreads();
  if (flag[0]) {
    float part = 0.f;
    for (int r = tid; r < NROW; r += 512)     // atomic read: cross-XCD safe
      part += SHIFT + __logf(atomicAdd(&wsS[r], 0.f)) - wsPosRow[r];
#pragma unroll
    for (int m = 1; m < 64; m <<= 1) part += __shfl_xor(part, m);
    float* red = (float*)(buf0 + 256);
    if (lane == 0) red[w] = part;
    __syncthreads();
    if (tid < 8) {
      float t = red[tid];
      t += __shfl_xor(t, 1);
      t += __shfl_xor(t, 2);
      t += __shfl_xor(t, 4);
      if (tid == 0) out[0] = t / (float)NROW;
    }
  }
}

extern "C" void kernel_launch(void* const* d_in, const int* in_sizes, int n_in,
                              void* d_out, int out_size, void* d_ws, size_t ws_size,
                              hipStream_t stream) {
  const float* f0 = (const float*)d_in[0];
  const float* f1 = (const float*)d_in[1];
  // d_in[2] (y) is unused by the reference computation.

  unsigned char* A = (unsigned char*)d_ws;                         // 4 MiB fp8
  unsigned char* B = A + (size_t)NROW * DDIM;                      // 4 MiB fp8
  float* wsS      = (float*)(B + (size_t)NROW * DDIM);             // [NROW]
  float* wsPosRow = wsS + NROW;                                    // [NROW]
  int*   wsCnt    = (int*)(wsPosRow + NROW);                       // [1]

  prep_kernel<<<NROW / 4, 256, 0, stream>>>(f0, f1, (unsigned int*)A,
                                            (unsigned int*)B, wsS, wsPosRow,
                                            wsCnt);
  sim_lse_kernel<<<256, 512, 0, stream>>>(A, B, wsS, wsPosRow, wsCnt,
                                          (float*)d_out);
}

// Round 27
// 48.034 us; speedup vs baseline: 1.6846x; 1.6846x over previous
//
#include <hip/hip_runtime.h>
#include <hip/hip_bf16.h>

typedef __attribute__((ext_vector_type(4)))  float f32x4;
typedef __attribute__((ext_vector_type(8)))  int   i32x8;
typedef __attribute__((ext_vector_type(4)))  int   i32x4;

static constexpr int NROW = 8192;
static constexpr int DDIM = 512;
static constexpr float INV_T = 10.0f;    // 1 / temperature
static constexpr float SHIFT = 70.0f;    // fixed logsumexp shift (logit max ~60)
// exp(acc*10 - 70) = exp2(acc*14.4269504 - 100.98865)
static constexpr float E2_SC = 14.4269504089f;
static constexpr float E2_BI = -100.988652759f;
static constexpr unsigned SCALE1 = 0x7F7F7F7Fu;   // e8m0 = 127 -> 2^0 = 1.0

__device__ __forceinline__ void gload_lds16(const void* gsrc, void* ldst) {
  __builtin_amdgcn_global_load_lds(
      (const __attribute__((address_space(1))) unsigned int*)gsrc,
      (__attribute__((address_space(3))) unsigned int*)ldst, 16, 0, 0);
}

// single-instruction v_exp_f32 (arg range here is [-187,-14]: no edge cases)
__device__ __forceinline__ float fast_exp2(float x) {
#if __has_builtin(__builtin_amdgcn_exp2f)
  return __builtin_amdgcn_exp2f(x);
#else
  float r;
  asm("v_exp_f32 %0, %1" : "=v"(r) : "v"(x));
  return r;
#endif
}

// pack 4 floats into 4 fp8 e4m3 bytes (gfx950: OCP encoding)
__device__ __forceinline__ unsigned int pack_fp8x4(float x, float y, float z, float w) {
  unsigned int r = 0;
  r = __builtin_amdgcn_cvt_pk_fp8_f32(x, y, r, false);  // bytes 0,1
  r = __builtin_amdgcn_cvt_pk_fp8_f32(z, w, r, true);   // bytes 2,3
  return r;
}

// ---------- prep: normalize anchors, cast to fp8, EXACT fp32 diagonal ----------
__global__ void prep_kernel(const float* __restrict__ f0,
                            const float* __restrict__ f1,
                            unsigned int* __restrict__ A,   // [NROW][DDIM] fp8
                            unsigned int* __restrict__ B,
                            float* __restrict__ wsS,        // [NROW] exp-sums (zeroed)
                            float* __restrict__ wsPosRow) { // [NROW] exact pos_i
  int gid  = blockIdx.x * blockDim.x + threadIdx.x;
  if (gid < NROW) wsS[gid] = 0.f;             // zero LSE accumulators
  int wid  = gid >> 6;                         // one wave per row
  int lane = threadIdx.x & 63;
  const float4* s0 = (const float4*)(f0 + (size_t)wid * (2 * DDIM));  // features[:,0,:]
  const float4* s1 = (const float4*)(f1 + (size_t)wid * (2 * DDIM));  // features1[:,0,:]
  float4 v0 = s0[lane], v1 = s0[lane + 64];
  float4 w0 = s1[lane], w1 = s1[lane + 64];
  float ss = v0.x * v0.x + v0.y * v0.y + v0.z * v0.z + v0.w * v0.w +
             v1.x * v1.x + v1.y * v1.y + v1.z * v1.z + v1.w * v1.w;
  float cc = v0.x * w0.x + v0.y * w0.y + v0.z * w0.z + v0.w * w0.w +
             v1.x * w1.x + v1.y * w1.y + v1.z * w1.z + v1.w * w1.w;
#pragma unroll
  for (int m = 1; m < 64; m <<= 1) {
    ss += __shfl_xor(ss, m);
    cc += __shfl_xor(cc, m);
  }
  float rn = rsqrtf(ss);
  if (lane == 0) wsPosRow[wid] = cc * rn * INV_T;   // exact fp32 diagonal logit
  A[wid * 128 + lane]      = pack_fp8x4(v0.x * rn, v0.y * rn, v0.z * rn, v0.w * rn);
  A[wid * 128 + 64 + lane] = pack_fp8x4(v1.x * rn, v1.y * rn, v1.z * rn, v1.w * rn);
  B[wid * 128 + lane]      = pack_fp8x4(w0.x, w0.y, w0.z, w0.w);
  B[wid * 128 + 64 + lane] = pack_fp8x4(w1.x, w1.y, w1.z, w1.w);
}

// ---------- fused S = A.B^T / T with fixed-shift LSE accumulation ----------
// PROVEN BEST (r24, 48.9 us total) — restored byte-identical after r25/r26
// regressions. 16x16x128 MX scales=1.0 (= plain fp8 numerics), 8 waves x
// M_wave=32 in the 512-thr/128-VGPR class (law #1: only cap-fitting shapes
// run 2 waves/SIMD), TRI-buffer counted-vmcnt never-drain pipeline (T3/T4):
// per tile {compute(t); STAGE(t+2); s_waitcnt vmcnt(4); s_barrier} — own
// t+1 loads landed, t+2's stay in flight across the barrier.
// C/D: col=lane&15, row=(lane>>4)*4+reg (HW-verified m89).
__global__ __launch_bounds__(512, 2) void sim_lse_kernel(
    const unsigned char* __restrict__ Ag,
    const unsigned char* __restrict__ Bg,
    float* __restrict__ wsS) {
  __shared__ __align__(16) char buf0[64 * 512];   // 32 KiB each; tiles t%3
  __shared__ __align__(16) char buf1[64 * 512];
  __shared__ __align__(16) char buf2[64 * 512];

  const int tid  = threadIdx.x;
  const int w    = tid >> 6;                 // wave 0..7
  const int lane = tid & 63;
  const int lr   = lane & 15;                // row (A) / col (B,D) within 16
  const int kg   = lane >> 4;                // k-group 0..3 (32 B each)

  const int p  = blockIdx.x >> 3;            // row panel 0..31 (256 rows)
  const int cs = blockIdx.x & 7;             // col split 0..7 (1024 cols)
  const int r0 = p * 256 + w * 32;           // this wave's first row (32 rows)
  const int c0 = cs * 1024;                  // first column of this split

  // staging (verbatim r8/r23): wave w stages row-pairs pr = it*8+w; lane
  // covers 16 B of row n = 2*pr + (lane>>5); src byte ((lane&31)<<4)^((n&7)<<4)
  const int h5      = lane >> 5;
  const int stg_off = ((lane & 31) << 4) ^ (((2 * w + h5) & 7) << 4);
  const int stg_row = h5;
  const int swz = (lr & 7) << 4;             // col&7 == lr&7 (16 | jb*16)

  // A fragments, K-resident, 2 row-blocks of 16:
  // aX[ks] = 32 B of A[r0 + X*16 + lr][ks*128 + kg*32 .. +32)
  i32x8 a0[4], a1[4];
  {
    const char* ar0 = (const char*)Ag + (size_t)(r0 + lr) * DDIM + kg * 32;
    const char* ar1 = (const char*)Ag + (size_t)(r0 + 16 + lr) * DDIM + kg * 32;
#pragma unroll
    for (int ks = 0; ks < 4; ks++) {
      a0[ks] = *(const i32x8*)(ar0 + ks * 128);
      a1[ks] = *(const i32x8*)(ar1 + ks * 128);
    }
  }

  float sums0[4], sums1[4];
#pragma unroll
  for (int r = 0; r < 4; r++) { sums0[r] = 0.f; sums1[r] = 0.f; }

#define STAGE(BUF, T)                                                          \
  {                                                                            \
    const char* gb = (const char*)Bg + (size_t)(c0 + (T) * 64) * DDIM;         \
    _Pragma("unroll")                                                          \
    for (int it = 0; it < 4; it++) {                                           \
      int pr = it * 8 + w;                                                     \
      gload_lds16(gb + (size_t)(2 * pr + stg_row) * DDIM + stg_off,            \
                  (char*)(BUF) + pr * 1024);                                   \
    }                                                                          \
  }

// One tile (64 cols = 4 jb of 16): per jb, 4 k-steps; B-frag shared by the
// two row-block chains (acc0/acc1 interleave).
#define MFMA_EPI(BUF)                                                          \
  {                                                                            \
    _Pragma("unroll")                                                          \
    for (int jb = 0; jb < 4; jb++) {                                           \
      const int cb = ((jb * 16 + lr) * 512 + kg * 32) ^ swz;                   \
      const char* p0  = (const char*)(BUF) + cb;                               \
      const char* p0x = (const char*)(BUF) + (cb ^ 16);                        \
      f32x4 acc0 = (f32x4){0.f, 0.f, 0.f, 0.f};                                \
      f32x4 acc1 = (f32x4){0.f, 0.f, 0.f, 0.f};                                \
      __builtin_amdgcn_s_setprio(1);                                           \
      _Pragma("unroll")                                                        \
      for (int ks = 0; ks < 4; ks++) {                                         \
        i32x8 bv = __builtin_shufflevector(                                    \
            *(const i32x4*)(p0 + ks * 128), *(const i32x4*)(p0x + ks * 128),   \
            0, 1, 2, 3, 4, 5, 6, 7);                                           \
        acc0 = __builtin_amdgcn_mfma_scale_f32_16x16x128_f8f6f4(               \
            a0[ks], bv, acc0, 0, 0, 0, SCALE1, 0, SCALE1);                     \
        acc1 = __builtin_amdgcn_mfma_scale_f32_16x16x128_f8f6f4(               \
            a1[ks], bv, acc1, 0, 0, 0, SCALE1, 0, SCALE1);                     \
      }                                                                        \
      __builtin_amdgcn_s_setprio(0);                                           \
      _Pragma("unroll")                                                        \
      for (int r = 0; r < 4; r++) {                                            \
        sums0[r] += fast_exp2(fmaf(acc0[r], E2_SC, E2_BI));                    \
        sums1[r] += fast_exp2(fmaf(acc1[r], E2_SC, E2_BI));                    \
      }                                                                        \
    }                                                                          \
  }

// counted-vmcnt barrier: own t+1 loads done, t+2's stay in flight.
#define WAITBAR4()                                                             \
  {                                                                            \
    asm volatile("s_waitcnt vmcnt(4)" ::: "memory");                           \
    __builtin_amdgcn_s_barrier();                                              \
  }
#define WAITBAR0()                                                             \
  {                                                                            \
    asm volatile("s_waitcnt vmcnt(0)" ::: "memory");                           \
    __builtin_amdgcn_s_barrier();                                              \
  }

  STAGE(buf0, 0);
  STAGE(buf1, 1);
  WAITBAR4();                                 // tile 0 landed; tile 1 in flight

#pragma unroll 1
  for (int i = 0; i < 4; i++) {               // tiles 3i .. 3i+2
    const int t = 3 * i;
    MFMA_EPI(buf0);  STAGE(buf2, t + 2);  WAITBAR4();
    MFMA_EPI(buf1);  STAGE(buf0, t + 3);  WAITBAR4();
    MFMA_EPI(buf2);  STAGE(buf1, t + 4);  WAITBAR4();
  }
  // tiles 12..15 (tiles 12,13 already staged by the loop)
  MFMA_EPI(buf0);  STAGE(buf2, 14);  WAITBAR4();
  MFMA_EPI(buf1);  STAGE(buf0, 15);  WAITBAR4();
  MFMA_EPI(buf2);  WAITBAR0();                // drain tile 15
  MFMA_EPI(buf0);

#undef STAGE
#undef MFMA_EPI
#undef WAITBAR4
#undef WAITBAR0

  // reduce over the 16 col-partition lanes (same kg); lane lr==0 commits.
  // Lane's rows: r0 + rb*16 + kg*4 + r  (C/D row = (lane>>4)*4 + reg, m89).
#pragma unroll
  for (int r = 0; r < 4; r++) {
    float s0 = sums0[r], s1 = sums1[r];
    s0 += __shfl_xor(s0, 1);  s1 += __shfl_xor(s1, 1);
    s0 += __shfl_xor(s0, 2);  s1 += __shfl_xor(s1, 2);
    s0 += __shfl_xor(s0, 4);  s1 += __shfl_xor(s1, 4);
    s0 += __shfl_xor(s0, 8);  s1 += __shfl_xor(s1, 8);
    if (lr == 0) {
      atomicAdd(&wsS[r0 + kg * 4 + r], s0);
      atomicAdd(&wsS[r0 + 16 + kg * 4 + r], s1);
    }
  }
}

// ---------- finalize: loss = mean(SHIFT + log(S_r) - pos_r) ----------
__global__ void finalize_kernel(const float* __restrict__ wsS,
                                const float* __restrict__ wsPosRow,
                                float* __restrict__ out) {
  __shared__ float red[16];
  float part = 0.f;
  for (int r = threadIdx.x; r < NROW; r += 1024)
    part += SHIFT + __logf(wsS[r]) - wsPosRow[r];
#pragma unroll
  for (int m = 1; m < 64; m <<= 1) part += __shfl_xor(part, m);
  if ((threadIdx.x & 63) == 0) red[threadIdx.x >> 6] = part;
  __syncthreads();
  if (threadIdx.x < 16) {
    float t = red[threadIdx.x];
#pragma unroll
    for (int m = 1; m < 16; m <<= 1) t += __shfl_xor(t, m);
    if (threadIdx.x == 0) out[0] = t / (float)NROW;
  }
}

extern "C" void kernel_launch(void* const* d_in, const int* in_sizes, int n_in,
                              void* d_out, int out_size, void* d_ws, size_t ws_size,
                              hipStream_t stream) {
  const float* f0 = (const float*)d_in[0];
  const float* f1 = (const float*)d_in[1];
  // d_in[2] (y) is unused by the reference computation.

  unsigned char* A = (unsigned char*)d_ws;                         // 4 MiB fp8
  unsigned char* B = A + (size_t)NROW * DDIM;                      // 4 MiB fp8
  float* wsS      = (float*)(B + (size_t)NROW * DDIM);             // [NROW]
  float* wsPosRow = wsS + NROW;                                    // [NROW]

  prep_kernel<<<NROW / 4, 256, 0, stream>>>(f0, f1, (unsigned int*)A,
                                            (unsigned int*)B, wsS, wsPosRow);
  sim_lse_kernel<<<256, 512, 0, stream>>>(A, B, wsS);
  finalize_kernel<<<1, 1024, 0, stream>>>(wsS, wsPosRow, (float*)d_out);
}